// Round 4
// baseline (659.702 us; speedup 1.0000x reference)
//
#include <hip/hip_runtime.h>

#define T_OBS 512
#define NTILE 3            // tiles per wave (4 L0-waves x 3 + 4 L1-waves x 3 = 24 tiles = 2x192 gate rows)
#define RSTRH 200          // halves per batch-row (=100 dw; 100 mod 32 = 4 -> only free n/n+8 alias; 16B-aligned)
#define L2E   1.44269504089f

typedef float    f32x4 __attribute__((ext_vector_type(4)));
typedef _Float16 f16x8 __attribute__((ext_vector_type(8)));

#define MF(A,B,C) __builtin_amdgcn_mfma_f32_16x16x32_f16(A, B, C, 0, 0, 0)

__device__ __forceinline__ unsigned f2h(float f) {
    union { _Float16 h; unsigned short u; } v; v.h = (_Float16)f;   // RNE
    return (unsigned)v.u;
}
// prescaled activations: weights/biases carry the log2e factors
__device__ __forceinline__ float sigm_p(float a) {   // a = -log2e * x
    return __builtin_amdgcn_rcpf(1.f + __builtin_amdgcn_exp2f(a));
}
__device__ __forceinline__ float tanh_p(float a) {   // a = 2*log2e * x
    return 1.f - 2.f * __builtin_amdgcn_rcpf(1.f + __builtin_amdgcn_exp2f(a));
}
__device__ __forceinline__ float tanh_r(float v) {   // real-unit tanh (cell state)
    return 1.f - 2.f * __builtin_amdgcn_rcpf(1.f + __builtin_amdgcn_exp2f(2.f * L2E * v));
}
__device__ __forceinline__ float lstm_act(const f32x4 a, float& c) {
    const float ig = sigm_p(a[0]);
    const float fg = sigm_p(a[1]);
    const float gg = tanh_p(a[2]);
    const float og = sigm_p(a[3]);
    c = fg * c + ig * gg;
    return og * tanh_r(c);
}

// LDS h-buffer per batch-row n (half indices within row, stride RSTRH):
//   [0..47] h0 par0 | [48..95] h0 par1 | [96..143] h1 par0 | [144..191] h1 par1
__global__ __launch_bounds__(512, 1) void lstm2_f16(
    const float* __restrict__ x,
    const float* __restrict__ Wih0, const float* __restrict__ Whh0,
    const float* __restrict__ bih0, const float* __restrict__ bhh0,
    const float* __restrict__ Wih1, const float* __restrict__ Whh1,
    const float* __restrict__ bih1, const float* __restrict__ bhh1,
    const float* __restrict__ Wlin, const float* __restrict__ blin,
    const int* __restrict__ fut,
    float* __restrict__ out)
{
    __shared__ __attribute__((aligned(16))) _Float16 s_h[16 * RSTRH];
    __shared__ __attribute__((aligned(16))) float s_pr[2][64];   // head partials, dbuf by parity

    unsigned* const s32 = (unsigned*)s_h;

    const int tid  = threadIdx.x;
    const int wave = tid >> 6;
    const int lane = tid & 63;
    const int n    = lane & 15;        // batch column
    const int rg   = lane >> 4;        // k-group / C row-group
    const bool isL1 = (wave >= 4);     // waves 0-3: layer 0; waves 4-7: layer 1
    const int  w    = wave & 3;        // role-local wave index

    for (int i = tid; i < 16 * RSTRH; i += 512) s_h[i] = (_Float16)0.f;

    // gate of this lane's A-rows: rp = 16m + n -> gate = n&3 (uniform per lane)
    const float sgl = ((n & 3) == 2) ? 2.f * L2E : -L2E;

    // ---- A fragments in registers, prescaled, fp16 hi/lo (2-term) ----
    // L0-wave: slabs s=0,1 cover K=64 (zero-padded past 48); L1: s=0..2 cover K=96 [Wih1|Whh1]
    f16x8 ah[NTILE][3], al[NTILE][3];
    #pragma unroll
    for (int i = 0; i < NTILE; ++i) {
        const int m  = 3 * w + i;
        const int rp = 16 * m + n;
        const int r0 = (rp & 3) * 48 + (rp >> 2);      // rows permuted: rp = u*4 + gate
        #pragma unroll
        for (int s = 0; s < 3; ++s)
            #pragma unroll
            for (int j = 0; j < 8; ++j) {
                const int k = 32 * s + 8 * rg + j;
                float v;
                if (isL1) v = ((k < 48) ? Wih1[r0 * 48 + k] : Whh1[r0 * 48 + (k - 48)]) * sgl;
                else      v = (s < 2 && k < 48) ? Whh0[r0 * 48 + k] * sgl : 0.f;
                const _Float16 hi = (_Float16)v;
                ah[i][s][j] = hi;
                al[i][s][j] = (_Float16)(v - (float)hi);
            }
    }

    const float sg4[4] = { -L2E, -L2E, 2.f * L2E, -L2E };   // (i,f,g,o)
    f32x4 bv[NTILE], wi0v[NTILE];
    float wlq[NTILE];
    int   dwp[NTILE];
    #pragma unroll
    for (int i = 0; i < NTILE; ++i) {
        const int u = 4 * (3 * w + i) + rg;
        dwp[i] = n * (RSTRH / 2) + 2 * (3 * w + i) + (rg >> 1);   // pair-dword base (region added later)
        wlq[i] = Wlin[u];
        #pragma unroll
        for (int g = 0; g < 4; ++g) {
            bv[i][g]   = (isL1 ? (bih1[g * 48 + u] + bhh1[g * 48 + u])
                               : (bih0[g * 48 + u] + bhh0[g * 48 + u])) * sg4[g];
            wi0v[i][g] = Wih0[g * 48 + u] * sg4[g];
        }
    }

    // B-fragment k-offsets (shared by both layers: L0's k>=48 cols hit zero A-weights)
    int koff[3];
    #pragma unroll
    for (int s = 0; s < 3; ++s) {
        const int k0 = 32 * s + 8 * rg;
        koff[s] = (k0 < 48) ? k0 : k0 + 48;   // k>=48 -> h1 region (+96 base, -48 k); always finite
    }

    const int F    = fut[0];
    const int TT   = T_OBS + F;
    const int bb0  = blockIdx.x * 16;
    const float bl = blin[0];
    const int xrow = (bb0 + n) * T_OBS;
    const int nb   = n * RSTRH;

    float cc[NTILE];
    #pragma unroll
    for (int i = 0; i < NTILE; ++i) cc[i] = 0.f;

    const f32x4 z4 = { 0.f, 0.f, 0.f, 0.f };

    __syncthreads();

    // ---- tick 0 (peeled): L0 step 0 with h0(-1)=0 -> gates = bias + wi0*x0 ----
    if (!isL1) {
        const float x0 = x[xrow];
        unsigned hw[NTILE];
        #pragma unroll
        for (int i = 0; i < NTILE; ++i) {
            const f32x4 a = bv[i] + wi0v[i] * x0;
            hw[i] = f2h(lstm_act(a, cc[i]));
        }
        #pragma unroll
        for (int i = 0; i < NTILE; ++i) {
            const unsigned pw = (unsigned)__shfl_xor((int)hw[i], 16);
            if (!(rg & 1)) s32[dwp[i] + 0] = hw[i] | (pw << 16);   // h0 par0
        }
    }
    __syncthreads();

    // ---- steady loop: tau = 1..511; L0 computes step tau, L1 computes step tau-1 ----
    for (int tau = 1; tau < T_OBS; ++tau) {
        const int cb = (tau & 1) * 48;
        const int pb = 48 - cb;
        const int rb = nb + pb;

        if (!isL1) {
            // deferred head output o(tau-2) (wave 0 lanes only)
            if (tau >= 2 && tid < 16) {
                const f32x4 p = *(const f32x4*)(&s_pr[(tau - 1) & 1][tid * 4]);
                out[(bb0 + tid) * TT + (tau - 2)] = p[0] + p[1] + p[2] + p[3] + bl;
            }
            const f16x8 bh0 = *(const f16x8*)(s_h + rb + koff[0]);
            const f16x8 bh1 = *(const f16x8*)(s_h + rb + koff[1]);
            const float inp = x[xrow + tau];
            f32x4 Aq[NTILE], Bq[NTILE];
            __builtin_amdgcn_s_setprio(1);
            #pragma unroll
            for (int i = 0; i < NTILE; ++i) {
                Aq[i] = MF(ah[i][0], bh0, bv[i]);
                Aq[i] = MF(al[i][0], bh0, Aq[i]);
                Bq[i] = MF(ah[i][1], bh1, z4);
                Bq[i] = MF(al[i][1], bh1, Bq[i]);
            }
            __builtin_amdgcn_s_setprio(0);
            unsigned hw[NTILE];
            #pragma unroll
            for (int i = 0; i < NTILE; ++i) {
                const f32x4 a = Aq[i] + Bq[i] + wi0v[i] * inp;
                hw[i] = f2h(lstm_act(a, cc[i]));
            }
            #pragma unroll
            for (int i = 0; i < NTILE; ++i) {
                const unsigned pw = (unsigned)__shfl_xor((int)hw[i], 16);
                if (!(rg & 1)) s32[dwp[i] + (cb >> 1)] = hw[i] | (pw << 16);
            }
        } else {
            f16x8 bh[3];
            #pragma unroll
            for (int s = 0; s < 3; ++s) bh[s] = *(const f16x8*)(s_h + rb + koff[s]);
            f32x4 Aq[NTILE], Bq[NTILE];
            __builtin_amdgcn_s_setprio(1);
            #pragma unroll
            for (int i = 0; i < NTILE; ++i) {
                Aq[i] = MF(ah[i][0], bh[0], bv[i]);
                Aq[i] = MF(al[i][0], bh[0], Aq[i]);
                Aq[i] = MF(ah[i][1], bh[1], Aq[i]);
                Bq[i] = MF(al[i][1], bh[1], z4);
                Bq[i] = MF(ah[i][2], bh[2], Bq[i]);
                Bq[i] = MF(al[i][2], bh[2], Bq[i]);
            }
            __builtin_amdgcn_s_setprio(0);
            float part = 0.f;
            unsigned hw[NTILE];
            #pragma unroll
            for (int i = 0; i < NTILE; ++i) {
                const f32x4 a = Aq[i] + Bq[i];
                const float h = lstm_act(a, cc[i]);
                hw[i] = f2h(h);
                part = fmaf(h, wlq[i], part);
            }
            #pragma unroll
            for (int i = 0; i < NTILE; ++i) {
                const unsigned pw = (unsigned)__shfl_xor((int)hw[i], 16);
                if (!(rg & 1)) s32[dwp[i] + 48 + (cb >> 1)] = hw[i] | (pw << 16);
            }
            part += __shfl_xor(part, 16);
            part += __shfl_xor(part, 32);
            if (lane < 16) s_pr[tau & 1][lane * 4 + w] = part;
        }
        __syncthreads();
    }

    // bridge: out(510) from s_pr parity 1 (written at tau=511)
    if (tid < 16) {
        const f32x4 p = *(const f32x4*)(&s_pr[1][tid * 4]);
        out[(bb0 + tid) * TT + (T_OBS - 2)] = p[0] + p[1] + p[2] + p[3] + bl;
    }

    // ---- AR loop: tau = 512..TT; o(tau-1) resolved mid-tick ----
    for (int tau = T_OBS; tau <= TT; ++tau) {
        const int cb = (tau & 1) * 48;
        const int pb = 48 - cb;
        const int rb = nb + pb;

        f32x4 Aq[NTILE], Bq[NTILE];
        if (isL1) {
            f16x8 bh[3];
            #pragma unroll
            for (int s = 0; s < 3; ++s) bh[s] = *(const f16x8*)(s_h + rb + koff[s]);
            __builtin_amdgcn_s_setprio(1);
            #pragma unroll
            for (int i = 0; i < NTILE; ++i) {
                Aq[i] = MF(ah[i][0], bh[0], bv[i]);
                Aq[i] = MF(al[i][0], bh[0], Aq[i]);
                Aq[i] = MF(ah[i][1], bh[1], Aq[i]);
                Bq[i] = MF(al[i][1], bh[1], z4);
                Bq[i] = MF(ah[i][2], bh[2], Bq[i]);
                Bq[i] = MF(al[i][2], bh[2], Bq[i]);
            }
            __builtin_amdgcn_s_setprio(0);
            float part = 0.f;
            unsigned hw[NTILE];
            #pragma unroll
            for (int i = 0; i < NTILE; ++i) {
                const f32x4 a = Aq[i] + Bq[i];
                const float h = lstm_act(a, cc[i]);
                hw[i] = f2h(h);
                part = fmaf(h, wlq[i], part);
            }
            #pragma unroll
            for (int i = 0; i < NTILE; ++i) {
                const unsigned pw = (unsigned)__shfl_xor((int)hw[i], 16);
                if (!(rg & 1)) s32[dwp[i] + 48 + (cb >> 1)] = hw[i] | (pw << 16);
            }
            part += __shfl_xor(part, 16);
            part += __shfl_xor(part, 32);
            if (lane < 16) s_pr[tau & 1][lane * 4 + w] = part;
        } else {
            const f16x8 bh0 = *(const f16x8*)(s_h + rb + koff[0]);
            const f16x8 bh1 = *(const f16x8*)(s_h + rb + koff[1]);
            __builtin_amdgcn_s_setprio(1);
            #pragma unroll
            for (int i = 0; i < NTILE; ++i) {
                Aq[i] = MF(ah[i][0], bh0, bv[i]);
                Aq[i] = MF(al[i][0], bh0, Aq[i]);
                Bq[i] = MF(ah[i][1], bh1, z4);
                Bq[i] = MF(al[i][1], bh1, Bq[i]);
            }
            __builtin_amdgcn_s_setprio(0);
        }
        __syncthreads();   // mid: s_pr (h1(tau-1) partials) ready

        if (!isL1) {
            const f32x4 p = *(const f32x4*)(&s_pr[tau & 1][n * 4]);
            const float o = p[0] + p[1] + p[2] + p[3] + bl;
            if (tid < 16) out[(bb0 + n) * TT + (tau - 1)] = o;
            if (tau < TT) {
                unsigned hw[NTILE];
                #pragma unroll
                for (int i = 0; i < NTILE; ++i) {
                    const f32x4 a = Aq[i] + Bq[i] + wi0v[i] * o;
                    hw[i] = f2h(lstm_act(a, cc[i]));
                }
                #pragma unroll
                for (int i = 0; i < NTILE; ++i) {
                    const unsigned pw = (unsigned)__shfl_xor((int)hw[i], 16);
                    if (!(rg & 1)) s32[dwp[i] + (cb >> 1)] = hw[i] | (pw << 16);
                }
            }
        }
        __syncthreads();
    }
}

extern "C" void kernel_launch(void* const* d_in, const int* in_sizes, int n_in,
                              void* d_out, int out_size, void* d_ws, size_t ws_size,
                              hipStream_t stream) {
    const float* x    = (const float*)d_in[0];
    const float* Wih0 = (const float*)d_in[1];
    const float* Whh0 = (const float*)d_in[2];
    const float* bih0 = (const float*)d_in[3];
    const float* bhh0 = (const float*)d_in[4];
    const float* Wih1 = (const float*)d_in[5];
    const float* Whh1 = (const float*)d_in[6];
    const float* bih1 = (const float*)d_in[7];
    const float* bhh1 = (const float*)d_in[8];
    const float* Wlin = (const float*)d_in[9];
    const float* blin = (const float*)d_in[10];
    const int*   fut  = (const int*)d_in[11];
    float* out = (float*)d_out;

    const int B    = in_sizes[0] / T_OBS;   // 4096
    const int grid = B / 16;                // 256 blocks -> 1 per CU, 8 waves = 2/SIMD
    lstm2_f16<<<grid, 512, 0, stream>>>(
        x, Wih0, Whh0, bih0, bhh0, Wih1, Whh1, bih1, bhh1, Wlin, blin, fut, out);
}

// Round 5
// 540.246 us; speedup vs baseline: 1.2211x; 1.2211x over previous
//
#include <hip/hip_runtime.h>

#define T_OBS 512
#define NTILE 3            // tiles per wave (4 L0-waves x 3 + 4 L1-waves x 3 = 24 tiles = 2x192 gate rows)
#define RSTRH 200          // halves per batch-row (=100 dw; only free n/n+8 2-way alias; 16B-aligned)
#define PSTR  20           // s_pr row stride in dwords (16B-aligned rows, n/n+8 2-way only)
#define L2E   1.44269504089f

typedef float    f32x4 __attribute__((ext_vector_type(4)));
typedef _Float16 f16x8 __attribute__((ext_vector_type(8)));

#define MF(A,B,C) __builtin_amdgcn_mfma_f32_16x16x32_f16(A, B, C, 0, 0, 0)

// prescaled gates: i,f,o carry -log2e; g carries +2*log2e.
// paired-rcp: one rcp serves (i,f); one serves (g,o); one for tanh(c). 5 exp2 + 3 rcp.
__device__ __forceinline__ float lstm_act(const f32x4 a, float& c) {
    const float Ei = __builtin_amdgcn_exp2f(a[0]);
    const float Ef = __builtin_amdgcn_exp2f(a[1]);
    const float Eg = __builtin_amdgcn_exp2f(a[2]);
    const float Eo = __builtin_amdgcn_exp2f(a[3]);
    const float ui = 1.f + Ei, uf = 1.f + Ef, ug = 1.f + Eg, uo = 1.f + Eo;
    const float r1 = __builtin_amdgcn_rcpf(ui * uf);
    const float ig = r1 * uf;                      // sigmoid(i)
    const float fg = r1 * ui;                      // sigmoid(f)
    const float r2 = __builtin_amdgcn_rcpf(ug * uo);
    const float og = r2 * ug;                      // sigmoid(o)
    const float gg = fmaf(r2 * uo, -2.f, 1.f);     // tanh(g)
    c = fg * c + ig * gg;
    const float Ec = __builtin_amdgcn_exp2f(2.f * L2E * c);
    const float th = fmaf(__builtin_amdgcn_rcpf(1.f + Ec), -2.f, 1.f);   // tanh(c)
    return og * th;
}

// LDS h-buffer per batch-row n (half indices within row, stride RSTRH):
//   [0..47] h0 par0 | [48..95] h0 par1 | [96..143] h1 par0 | [144..191] h1 par1
__global__ __launch_bounds__(512, 1) void lstm2_v5(
    const float* __restrict__ x,
    const float* __restrict__ Wih0, const float* __restrict__ Whh0,
    const float* __restrict__ bih0, const float* __restrict__ bhh0,
    const float* __restrict__ Wih1, const float* __restrict__ Whh1,
    const float* __restrict__ bih1, const float* __restrict__ bhh1,
    const float* __restrict__ Wlin, const float* __restrict__ blin,
    const int* __restrict__ fut,
    float* __restrict__ out)
{
    __shared__ __attribute__((aligned(16))) _Float16 s_h[16 * RSTRH];
    __shared__ __attribute__((aligned(16))) float s_pr[2][16 * PSTR];   // raw head partials, dbuf

    const int tid  = threadIdx.x;
    const int wave = tid >> 6;
    const int lane = tid & 63;
    const int n    = lane & 15;        // batch column
    const int rg   = lane >> 4;        // k-group / C row-group
    const bool isL1 = (wave >= 4);     // waves 0-3: layer 0; waves 4-7: layer 1
    const int  w    = wave & 3;        // role-local wave index

    for (int i = tid; i < 16 * RSTRH; i += 512) s_h[i] = (_Float16)0.f;

    // gate of this lane's A-rows: rp = 16m + n -> gate = n&3 (uniform per lane)
    const float sgl = ((n & 3) == 2) ? 2.f * L2E : -L2E;

    // ---- A fragments in registers, prescaled, fp16 hi/lo (2-term) ----
    // L0-wave: slabs s=0,1 cover K=64 (zero-padded past 48); L1: s=0..2 cover K=96 [Wih1|Whh1]
    f16x8 ah[NTILE][3], al[NTILE][3];
    #pragma unroll
    for (int i = 0; i < NTILE; ++i) {
        const int m  = 3 * w + i;
        const int rp = 16 * m + n;
        const int r0 = (rp & 3) * 48 + (rp >> 2);      // rows permuted: rp = u*4 + gate
        #pragma unroll
        for (int s = 0; s < 3; ++s)
            #pragma unroll
            for (int j = 0; j < 8; ++j) {
                const int k = 32 * s + 8 * rg + j;
                float v;
                if (isL1) v = ((k < 48) ? Wih1[r0 * 48 + k] : Whh1[r0 * 48 + (k - 48)]) * sgl;
                else      v = (s < 2 && k < 48) ? Whh0[r0 * 48 + k] * sgl : 0.f;
                const _Float16 hi = (_Float16)v;
                ah[i][s][j] = hi;
                al[i][s][j] = (_Float16)(v - (float)hi);
            }
    }

    const float sg4[4] = { -L2E, -L2E, 2.f * L2E, -L2E };   // (i,f,g,o)
    f32x4 bv[NTILE], wi0v[NTILE];
    float wlq[NTILE];
    int   hu[NTILE];
    #pragma unroll
    for (int i = 0; i < NTILE; ++i) {
        const int u = 4 * (3 * w + i) + rg;
        hu[i]  = u;
        wlq[i] = Wlin[u];
        #pragma unroll
        for (int g = 0; g < 4; ++g) {
            bv[i][g]   = (isL1 ? (bih1[g * 48 + u] + bhh1[g * 48 + u])
                               : (bih0[g * 48 + u] + bhh0[g * 48 + u])) * sg4[g];
            wi0v[i][g] = Wih0[g * 48 + u] * sg4[g];
        }
    }

    // B-fragment k-offsets (shared by both layers: L0's k>=48 cols hit zero A-weights)
    int koff[3];
    #pragma unroll
    for (int s = 0; s < 3; ++s) {
        const int k0 = 32 * s + 8 * rg;
        koff[s] = (k0 < 48) ? k0 : k0 + 48;   // k>=48 -> h1 region (+96 base, -48 k)
    }

    const int F    = fut[0];
    const int TT   = T_OBS + F;
    const int bb0  = blockIdx.x * 16;
    const float bl = blin[0];
    const int xrow = (bb0 + n) * T_OBS;
    const int nb   = n * RSTRH;
    const int prh  = n * PSTR + w * 4 + rg;   // scatter address for raw head partials

    float cc[NTILE];
    #pragma unroll
    for (int i = 0; i < NTILE; ++i) cc[i] = 0.f;

    const f32x4 z4 = { 0.f, 0.f, 0.f, 0.f };

    __syncthreads();

    // ---- tick 0 (peeled): L0 step 0 with h0(-1)=0 -> gates = bias + wi0*x0 ----
    if (!isL1) {
        const float x0 = x[xrow];
        #pragma unroll
        for (int i = 0; i < NTILE; ++i) {
            const f32x4 a = bv[i] + wi0v[i] * x0;
            s_h[nb + hu[i]] = (_Float16)lstm_act(a, cc[i]);   // h0 par0
        }
    }
    __syncthreads();

    float xcur = 0.f;
    if (!isL1) xcur = x[xrow + 1];

    // ---- steady loop: tau = 1..511; L0 computes step tau, L1 computes step tau-1 ----
    for (int tau = 1; tau < T_OBS; ++tau) {
        const int cb = (tau & 1) * 48;
        const int pb = 48 - cb;
        const int rb = nb + pb;

        if (!isL1) {
            // prefetch next x (covers full tick of latency)
            const float xnxt = x[xrow + ((tau + 1 < T_OBS) ? tau + 1 : T_OBS - 1)];
            // deferred head output o(tau-2): gather 16 raw partials (off critical path)
            if (tau >= 2 && tid < 16) {
                const float* pr = &s_pr[(tau - 1) & 1][tid * PSTR];
                const f32x4 s = *(const f32x4*)(pr) + *(const f32x4*)(pr + 4)
                              + *(const f32x4*)(pr + 8) + *(const f32x4*)(pr + 12);
                out[(bb0 + tid) * TT + (tau - 2)] = s[0] + s[1] + s[2] + s[3] + bl;
            }
            const f16x8 bh0 = *(const f16x8*)(s_h + rb + koff[0]);
            const f16x8 bh1 = *(const f16x8*)(s_h + rb + koff[1]);
            f32x4 Aq[NTILE], Bq[NTILE];
            #pragma unroll
            for (int i = 0; i < NTILE; ++i) {
                Aq[i] = MF(ah[i][0], bh0, bv[i]);
                Aq[i] = MF(al[i][0], bh0, Aq[i]);
                Bq[i] = MF(ah[i][1], bh1, z4);
                Bq[i] = MF(al[i][1], bh1, Bq[i]);
            }
            #pragma unroll
            for (int i = 0; i < NTILE; ++i) {
                const f32x4 a = Aq[i] + Bq[i] + wi0v[i] * xcur;
                s_h[nb + cb + hu[i]] = (_Float16)lstm_act(a, cc[i]);
            }
            xcur = xnxt;
        } else {
            f16x8 bh[3];
            #pragma unroll
            for (int s = 0; s < 3; ++s) bh[s] = *(const f16x8*)(s_h + rb + koff[s]);
            f32x4 Aq[NTILE], Bq[NTILE];
            #pragma unroll
            for (int i = 0; i < NTILE; ++i) {
                Aq[i] = MF(ah[i][0], bh[0], bv[i]);
                Aq[i] = MF(al[i][0], bh[0], Aq[i]);
                Aq[i] = MF(ah[i][1], bh[1], Aq[i]);
                Bq[i] = MF(al[i][1], bh[1], z4);
                Bq[i] = MF(ah[i][2], bh[2], Bq[i]);
                Bq[i] = MF(al[i][2], bh[2], Bq[i]);
            }
            float part = 0.f;
            #pragma unroll
            for (int i = 0; i < NTILE; ++i) {
                const f32x4 a = Aq[i] + Bq[i];
                const float h = lstm_act(a, cc[i]);
                s_h[nb + 96 + cb + hu[i]] = (_Float16)h;
                part = fmaf(h, wlq[i], part);
            }
            s_pr[tau & 1][prh] = part;   // raw scatter, no shfl
        }
        __syncthreads();
    }

    // bridge: out(510) from s_pr parity 1 (written at tau=511)
    if (tid < 16) {
        const float* pr = &s_pr[1][tid * PSTR];
        const f32x4 s = *(const f32x4*)(pr) + *(const f32x4*)(pr + 4)
                      + *(const f32x4*)(pr + 8) + *(const f32x4*)(pr + 12);
        out[(bb0 + tid) * TT + (T_OBS - 2)] = s[0] + s[1] + s[2] + s[3] + bl;
    }

    // ---- AR loop: tau = 512..TT; o(tau-1) resolved mid-tick ----
    for (int tau = T_OBS; tau <= TT; ++tau) {
        const int cb = (tau & 1) * 48;
        const int pb = 48 - cb;
        const int rb = nb + pb;

        f32x4 Aq[NTILE], Bq[NTILE];
        if (isL1) {
            f16x8 bh[3];
            #pragma unroll
            for (int s = 0; s < 3; ++s) bh[s] = *(const f16x8*)(s_h + rb + koff[s]);
            #pragma unroll
            for (int i = 0; i < NTILE; ++i) {
                Aq[i] = MF(ah[i][0], bh[0], bv[i]);
                Aq[i] = MF(al[i][0], bh[0], Aq[i]);
                Aq[i] = MF(ah[i][1], bh[1], Aq[i]);
                Bq[i] = MF(al[i][1], bh[1], z4);
                Bq[i] = MF(ah[i][2], bh[2], Bq[i]);
                Bq[i] = MF(al[i][2], bh[2], Bq[i]);
            }
            float part = 0.f;
            #pragma unroll
            for (int i = 0; i < NTILE; ++i) {
                const f32x4 a = Aq[i] + Bq[i];
                const float h = lstm_act(a, cc[i]);
                s_h[nb + 96 + cb + hu[i]] = (_Float16)h;
                part = fmaf(h, wlq[i], part);
            }
            s_pr[tau & 1][prh] = part;
        } else {
            const f16x8 bh0 = *(const f16x8*)(s_h + rb + koff[0]);
            const f16x8 bh1 = *(const f16x8*)(s_h + rb + koff[1]);
            #pragma unroll
            for (int i = 0; i < NTILE; ++i) {
                Aq[i] = MF(ah[i][0], bh0, bv[i]);
                Aq[i] = MF(al[i][0], bh0, Aq[i]);
                Bq[i] = MF(ah[i][1], bh1, z4);
                Bq[i] = MF(al[i][1], bh1, Bq[i]);
            }
        }
        __syncthreads();   // mid: s_pr (h1(tau-1) partials) ready

        if (!isL1) {
            const float* pr = &s_pr[tau & 1][n * PSTR];
            const f32x4 s = *(const f32x4*)(pr) + *(const f32x4*)(pr + 4)
                          + *(const f32x4*)(pr + 8) + *(const f32x4*)(pr + 12);
            const float o = s[0] + s[1] + s[2] + s[3] + bl;
            if (tid < 16) out[(bb0 + n) * TT + (tau - 1)] = o;
            if (tau < TT) {
                #pragma unroll
                for (int i = 0; i < NTILE; ++i) {
                    const f32x4 a = Aq[i] + Bq[i] + wi0v[i] * o;
                    s_h[nb + cb + hu[i]] = (_Float16)lstm_act(a, cc[i]);
                }
            }
        }
        __syncthreads();
    }
}

extern "C" void kernel_launch(void* const* d_in, const int* in_sizes, int n_in,
                              void* d_out, int out_size, void* d_ws, size_t ws_size,
                              hipStream_t stream) {
    const float* x    = (const float*)d_in[0];
    const float* Wih0 = (const float*)d_in[1];
    const float* Whh0 = (const float*)d_in[2];
    const float* bih0 = (const float*)d_in[3];
    const float* bhh0 = (const float*)d_in[4];
    const float* Wih1 = (const float*)d_in[5];
    const float* Whh1 = (const float*)d_in[6];
    const float* bih1 = (const float*)d_in[7];
    const float* bhh1 = (const float*)d_in[8];
    const float* Wlin = (const float*)d_in[9];
    const float* blin = (const float*)d_in[10];
    const int*   fut  = (const int*)d_in[11];
    float* out = (float*)d_out;

    const int B    = in_sizes[0] / T_OBS;   // 4096
    const int grid = B / 16;                // 256 blocks -> 1 per CU, 8 waves = 2/SIMD
    lstm2_v5<<<grid, 512, 0, stream>>>(
        x, Wih0, Whh0, bih0, bhh0, Wih1, Whh1, bih1, bhh1, Wlin, blin, fut, out);
}